// Round 6
// baseline (3457.183 us; speedup 1.0000x reference)
//
#include <hip/hip_runtime.h>
#include <hip/hip_bf16.h>
#include <stdint.h>

#define NB 128
#define NT 512
#define NI 256
#define NH 256
#define NG 768          // 3*NH
#define NGRP 16         // batch groups (8 batches each)
#define RING 32         // FIFO ring slots
#define LAG 12          // startup lag per pipeline stage (steps)

typedef unsigned int u32;
typedef unsigned long long u64;
typedef unsigned short u16;
typedef __attribute__((ext_vector_type(8))) short short8;
typedef __attribute__((ext_vector_type(4))) float f32x4;

__device__ __forceinline__ float lo_bf(u32 u){ return __uint_as_float(u << 16); }
__device__ __forceinline__ float hi_bf(u32 u){ return __uint_as_float(u & 0xffff0000u); }
__device__ __forceinline__ u16 f2bf(float f){
  u32 u = __float_as_uint(f);
  u += 0x7fffu + ((u >> 16) & 1u);   // RNE
  return (u16)(u >> 16);
}
__device__ __forceinline__ u32 pack2(float a, float b){
  return (u32)f2bf(a) | ((u32)f2bf(b) << 16);
}
__device__ __forceinline__ u32 pack_rne(float a, float b){
  u32 ua = __float_as_uint(a), ub = __float_as_uint(b);
  ua += 0x7fffu + ((ua >> 16) & 1u);
  ub += 0x7fffu + ((ub >> 16) & 1u);
  return (ua >> 16) | (ub & 0xffff0000u);
}
__device__ __forceinline__ u64 pack4(const f32x4& v){
  u32 a = pack_rne(v[0], v[1]), b = pack_rne(v[2], v[3]);
  return (u64)a | ((u64)b << 32);
}
__device__ __forceinline__ float sigf(float v){
  return __builtin_amdgcn_rcpf(1.f + __expf(-v));
}
__device__ __forceinline__ float tanhf_(float u){
  float e = __expf(2.f*u);
  return 1.f - 2.f*__builtin_amdgcn_rcpf(e + 1.f);
}
__device__ __forceinline__ void gload_lds16(const void* g, void* l){
  __builtin_amdgcn_global_load_lds((const __attribute__((address_space(1))) void*)g,
                                   (__attribute__((address_space(3))) void*)l, 16, 0, 0);
}
__device__ __forceinline__ void st_agent(u64* p, u64 v){
  __hip_atomic_store(p, v, __ATOMIC_RELAXED, __HIP_MEMORY_SCOPE_AGENT);
}
__device__ __forceinline__ u64 ld_agent(const u64* p){
  return __hip_atomic_load(p, __ATOMIC_RELAXED, __HIP_MEMORY_SCOPE_AGENT);
}
__device__ __forceinline__ u32 spin_ge(u32* p, u32 target, u32 shadow){
  while (shadow < target) {
    shadow = __hip_atomic_load(p, __ATOMIC_ACQUIRE, __HIP_MEMORY_SCOPE_AGENT);
    if (shadow >= target) break;
    __builtin_amdgcn_s_sleep(2);
  }
  return shadow;
}
// resident 768x256 weight slice -> 48 A-frags per wave (rows g*NH+32w+jj*16+c)
__device__ __forceinline__ void load_frags(const float* W, int w, int c, int q,
                                           short8 wf[3][2][8]){
  #pragma unroll
  for (int g = 0; g < 3; ++g)
    #pragma unroll
    for (int jj = 0; jj < 2; ++jj) {
      const float* src = W + ((size_t)(g*NH + 32*w + jj*16 + c))*NI + q*8;
      #pragma unroll
      for (int kb = 0; kb < 8; ++kb) {
        float4 f0 = *(const float4*)(src + kb*32);
        float4 f1 = *(const float4*)(src + kb*32 + 4);
        short8 s;
        s[0]=(short)f2bf(f0.x); s[1]=(short)f2bf(f0.y);
        s[2]=(short)f2bf(f0.z); s[3]=(short)f2bf(f0.w);
        s[4]=(short)f2bf(f1.x); s[5]=(short)f2bf(f1.y);
        s[6]=(short)f2bf(f1.z); s[7]=(short)f2bf(f1.w);
        wf[g][jj][kb] = s;
      }
    }
}

// ---------------------------------------------------------------------------
__global__ void convert_kernel(const float* __restrict__ x,
    const float* __restrict__ Wih0,
    const float* __restrict__ bih0, const float* __restrict__ bhh0,
    u16* __restrict__ xbf, u16* __restrict__ w0bf, float* __restrict__ bias0)
{
  const int NX4 = NB*NT*NI/4, NW4 = NG*NH/4;
  int gid = blockIdx.x*blockDim.x + threadIdx.x;
  for (int i = gid; i < NX4 + NW4; i += gridDim.x*blockDim.x) {
    const float* s; u16* d; int o;
    if (i < NX4) { s = x;    d = xbf;  o = i; }
    else         { s = Wih0; d = w0bf; o = i - NX4; }
    float4 v = *(const float4*)(s + (size_t)o*4);
    uint2 pk; pk.x = pack2(v.x, v.y); pk.y = pack2(v.z, v.w);
    *(uint2*)&d[(size_t)o*4] = pk;
  }
  if (gid < NG) bias0[gid] = bih0[gid] + (gid < 2*NH ? bhh0[gid] : 0.f);
}

// ---------------------------------------------------------------------------
// xproj0[m][g] = sum_k xbf[m][k] * w0bf[g][k] + bias0[g]
// ---------------------------------------------------------------------------
__global__ __launch_bounds__(256, 2) void gemm_proj(const u16* __restrict__ A,
    const u16* __restrict__ W, const float* __restrict__ bias, u16* __restrict__ out)
{
  const int mt = blockIdx.x / 24, nt = blockIdx.x % 24;
  __shared__ __align__(16) u16 As[64*256];
  __shared__ __align__(16) u16 Bs[32*256];
  const int tid = threadIdx.x;
  const u16* Ag = A + (size_t)mt*64*256;
  const u16* Wg = W + (size_t)nt*32*256;
  #pragma unroll
  for (int i = 0; i < 8; ++i) {
    int ca = tid + 256*i, row = ca >> 5, sl = ca & 31;
    gload_lds16(Ag + row*256 + ((sl ^ (row&7))<<3), &As[ca<<3]);
  }
  #pragma unroll
  for (int i = 0; i < 4; ++i) {
    int cb = tid + 256*i, row = cb >> 5, sl = cb & 31;
    gload_lds16(Wg + row*256 + ((sl ^ (row&7))<<3), &Bs[cb<<3]);
  }
  __syncthreads();
  const int w = tid >> 6, l = tid & 63, c = l & 15, q = l >> 4;
  f32x4 acc0 = {0.f,0.f,0.f,0.f}, acc1 = acc0;
  const int arow = w*16 + c;
  #pragma unroll
  for (int kb = 0; kb < 8; ++kb) {
    int ks = kb*4 + q;
    short8 af  = *(const short8*)&As[arow*256 + ((ks ^ (arow&7))<<3)];
    short8 bf0 = *(const short8*)&Bs[c*256        + ((ks ^ (c&7))<<3)];
    short8 bf1 = *(const short8*)&Bs[(16+c)*256   + ((ks ^ ((16+c)&7))<<3)];
    acc0 = __builtin_amdgcn_mfma_f32_16x16x32_bf16(af, bf0, acc0, 0,0,0);
    acc1 = __builtin_amdgcn_mfma_f32_16x16x32_bf16(af, bf1, acc1, 0,0,0);
  }
  #pragma unroll
  for (int nf = 0; nf < 2; ++nf) {
    int g = nt*32 + nf*16 + c;
    float bs = bias[g];
    f32x4 av = nf ? acc1 : acc0;
    #pragma unroll
    for (int r = 0; r < 4; ++r) {
      int m = mt*64 + w*16 + q*4 + r;
      out[(size_t)m*NG + g] = f2bf(av[r] + bs);
    }
  }
}

// ---------------------------------------------------------------------------
// 3-stage layer pipeline with startup LAG decoupling. 48 wgs x 512 thr.
// role = blockIdx>>4 (0:rec0 1:proj1 2:rec1), g_ = blockIdx&15.
// ---------------------------------------------------------------------------
__global__ __launch_bounds__(512, 1) void pipeline_kernel(
    const u16*  __restrict__ xproj,   // [NB*NT][768] bf16 (bias0 folded)
    const float* __restrict__ Whh0, const float* __restrict__ bhh0,
    const float* __restrict__ Wih1, const float* __restrict__ bih1,
    const float* __restrict__ bhh1, const float* __restrict__ Whh1,
    u16* __restrict__ hT,             // [NB][NH] bf16
    u16* __restrict__ fifo_h0,        // [NGRP][RING][4096] u16 (8KB frag images)
    u16* __restrict__ fifo_xp,        // [NGRP][RING][8*NG] bf16 (12KB slots)
    u32* __restrict__ cnts)           // [3][NGRP][32]
{
  const int role = blockIdx.x >> 4;
  const int g_   = blockIdx.x & 15;
  const int b0   = g_*8;
  const int tid = threadIdx.x;
  const int w = tid >> 6, l = tid & 63, c = l & 15, q = l >> 4;

  u32* cntA = cnts + (0*NGRP + g_)*32;
  u32* cntB = cnts + (1*NGRP + g_)*32;
  u32* cntC = cnts + (2*NGRP + g_)*32;
  u16* slots_h0 = fifo_h0 + (size_t)g_*RING*4096;
  u16* slots_xp = fifo_xp + (size_t)g_*RING*8*NG;

  __shared__ __align__(16) u16 hfrag[2][8][512];   // 16 KB
  for (int i = tid; i < 4096; i += 512) ((u32*)hfrag)[i] = 0u;
  __syncthreads();

  if (role == 0) {
    // ================= A: layer-0 recurrence (R3 engine) ==================
    short8 wf[3][2][8];
    load_frags(Whh0, w, c, q, wf);
    float4 bt0 = *(const float4*)&bhh0[2*NH + 32*w + q*4];
    float4 bt1 = *(const float4*)&bhh0[2*NH + 32*w + q*4 + 16];
    f32x4 bhn0; bhn0[0]=bt0.x; bhn0[1]=bt0.y; bhn0[2]=bt0.z; bhn0[3]=bt0.w;
    f32x4 bhn1; bhn1[0]=bt1.x; bhn1[1]=bt1.y; bhn1[2]=bt1.z; bhn1[3]=bt1.w;
    const int jh = c >> 3;
    const bool lo8 = (jh == 0);
    const int bb = b0 + (c & 7);
    const int jb = 32*w + jh*16 + q*4;
    const u16* xptr = xproj + (size_t)bb*NT*NG + jb;
    uint2 xpr = *(const uint2*)(xptr);
    uint2 xpz = *(const uint2*)(xptr + NH);
    uint2 xpn = *(const uint2*)(xptr + 2*NH);
    const u16* x1 = xptr + NG;
    uint2 pfr = *(const uint2*)(x1);
    uint2 pfz = *(const uint2*)(x1 + NH);
    uint2 pfn = *(const uint2*)(x1 + 2*NH);
    uint2 hpk; hpk.x = 0u; hpk.y = 0u;
    const int lp = (c&7) + 16*(2*jh + (q>>1));
    const int foff = w*512 + lp*8 + (q&1)*4;     // u16 units in 8KB slot
    u32 shadowB = 0;

    #pragma unroll 1
    for (int t = 0; t < NT; ++t) {
      const int cur = t & 1, nxt = cur ^ 1;
      short8 bfr[8];
      #pragma unroll
      for (int kb = 0; kb < 8; ++kb) bfr[kb] = *(const short8*)&hfrag[cur][kb][l*8];
      f32x4 z4 = {0.f,0.f,0.f,0.f};
      f32x4 ar0 = z4, az0 = z4, ar1 = z4, az1 = z4;
      f32x4 an0 = bhn0, an1 = bhn1;
      #pragma unroll
      for (int kb = 0; kb < 8; ++kb) {
        short8 bv = bfr[kb];
        ar0 = __builtin_amdgcn_mfma_f32_16x16x32_bf16(wf[0][0][kb], bv, ar0, 0,0,0);
        az0 = __builtin_amdgcn_mfma_f32_16x16x32_bf16(wf[1][0][kb], bv, az0, 0,0,0);
        an0 = __builtin_amdgcn_mfma_f32_16x16x32_bf16(wf[2][0][kb], bv, an0, 0,0,0);
        ar1 = __builtin_amdgcn_mfma_f32_16x16x32_bf16(wf[0][1][kb], bv, ar1, 0,0,0);
        az1 = __builtin_amdgcn_mfma_f32_16x16x32_bf16(wf[1][1][kb], bv, az1, 0,0,0);
        an1 = __builtin_amdgcn_mfma_f32_16x16x32_bf16(wf[2][1][kb], bv, an1, 0,0,0);
      }
      float hv[4];
      #pragma unroll
      for (int r = 0; r < 4; ++r) {
        float arv = lo8 ? ar0[r] : ar1[r];
        float azv = lo8 ? az0[r] : az1[r];
        float anv = lo8 ? an0[r] : an1[r];
        u32 xrw = (r < 2) ? xpr.x : xpr.y;
        u32 xzw = (r < 2) ? xpz.x : xpz.y;
        u32 xnw = (r < 2) ? xpn.x : xpn.y;
        u32 hpw = (r < 2) ? hpk.x : hpk.y;
        float xr = (r & 1) ? hi_bf(xrw) : lo_bf(xrw);
        float xz = (r & 1) ? hi_bf(xzw) : lo_bf(xzw);
        float xn = (r & 1) ? hi_bf(xnw) : lo_bf(xnw);
        float hp = (r & 1) ? hi_bf(hpw) : lo_bf(hpw);
        float rr = sigf(xr + arv);
        float zz = sigf(xz + azv);
        float nn = tanhf_(__builtin_fmaf(rr, anv, xn));
        hv[r] = __builtin_fmaf(zz, hp - nn, nn);
      }
      hpk.x = pack_rne(hv[0], hv[1]);
      hpk.y = pack_rne(hv[2], hv[3]);

      u16* hdst = &hfrag[nxt][w][lp*8 + (q&1)*4];
      *(uint2*)hdst        = hpk;
      *(uint2*)(hdst + 64) = hpk;

      // ring-full guard (rare): B must be done reading slot t-32
      if (t >= 29) {
        u32 tgt = 8u*(u32)(t - 28);
        if (shadowB < tgt) shadowB = spin_ge(cntB, tgt, shadowB);
      }
      // publish h0 frag image (8B agent stores, both column copies)
      u64 hv64 = (u64)hpk.x | ((u64)hpk.y << 32);
      u16* sb = slots_h0 + (size_t)(t & (RING-1))*4096 + foff;
      st_agent((u64*)sb, hv64);
      st_agent((u64*)(sb + 64), hv64);
      if (l == 0)
        __hip_atomic_fetch_add(cntA, 1u, __ATOMIC_RELEASE, __HIP_MEMORY_SCOPE_AGENT);

      // depth-2 xproj prefetch
      xpr = pfr; xpz = pfz; xpn = pfn;
      if (t + 2 < NT) {
        const u16* xn_ = xptr + (size_t)(t+2)*NG;
        pfr = *(const uint2*)(xn_);
        pfz = *(const uint2*)(xn_ + NH);
        pfn = *(const uint2*)(xn_ + 2*NH);
      }
      asm volatile("s_waitcnt lgkmcnt(0)" ::: "memory");
      __builtin_amdgcn_s_barrier();
      __builtin_amdgcn_sched_barrier(0);
    }

  } else if (role == 1) {
    // ================= B: xp1[t] = Wih1 * h0[t] + bias1 ===================
    short8 wf[3][2][8];
    load_frags(Wih1, w, c, q, wf);
    f32x4 bias[3][2];
    #pragma unroll
    for (int g = 0; g < 3; ++g)
      #pragma unroll
      for (int jj = 0; jj < 2; ++jj) {
        int grow = g*NH + 32*w + jj*16 + q*4;
        float4 bi = *(const float4*)&bih1[grow];
        f32x4 bv; bv[0]=bi.x; bv[1]=bi.y; bv[2]=bi.z; bv[3]=bi.w;
        if (g < 2) {
          float4 bh = *(const float4*)&bhh1[grow];
          bv[0]+=bh.x; bv[1]+=bh.y; bv[2]+=bh.z; bv[3]+=bh.w;
        }
        bias[g][jj] = bv;
      }
    const int jj = c >> 3;
    u32 shadowA = 0, shadowC = 0;
    // ---- startup LAG: let A get LAG steps ahead before we consume ----
    shadowA = spin_ge(cntA, 8u*LAG, shadowA);
    const u16* s0 = slots_h0 + 0*4096 + tid*8;
    u64 wc0 = ld_agent((const u64*)s0), wc1 = ld_agent((const u64*)(s0 + 4));
    const u16* s1 = slots_h0 + 1*4096 + tid*8;
    u64 pf0 = ld_agent((const u64*)s1), pf1 = ld_agent((const u64*)(s1 + 4));

    #pragma unroll 1
    for (int t = 0; t < NT; ++t) {
      const int buf = t & 1;
      uint4 wv; wv.x=(u32)wc0; wv.y=(u32)(wc0>>32); wv.z=(u32)wc1; wv.w=(u32)(wc1>>32);
      *(uint4*)&((u16*)hfrag)[buf*4096 + tid*8] = wv;
      asm volatile("s_waitcnt lgkmcnt(0)" ::: "memory");
      __builtin_amdgcn_s_barrier();
      __builtin_amdgcn_sched_barrier(0);

      f32x4 a00 = bias[0][0], a10 = bias[1][0], a20 = bias[2][0];
      f32x4 a01 = bias[0][1], a11 = bias[1][1], a21 = bias[2][1];
      #pragma unroll
      for (int kb = 0; kb < 8; ++kb) {
        short8 bv = *(const short8*)&hfrag[buf][kb][l*8];
        a00 = __builtin_amdgcn_mfma_f32_16x16x32_bf16(wf[0][0][kb], bv, a00, 0,0,0);
        a10 = __builtin_amdgcn_mfma_f32_16x16x32_bf16(wf[1][0][kb], bv, a10, 0,0,0);
        a20 = __builtin_amdgcn_mfma_f32_16x16x32_bf16(wf[2][0][kb], bv, a20, 0,0,0);
        a01 = __builtin_amdgcn_mfma_f32_16x16x32_bf16(wf[0][1][kb], bv, a01, 0,0,0);
        a11 = __builtin_amdgcn_mfma_f32_16x16x32_bf16(wf[1][1][kb], bv, a11, 0,0,0);
        a21 = __builtin_amdgcn_mfma_f32_16x16x32_bf16(wf[2][1][kb], bv, a21, 0,0,0);
      }
      f32x4 v0 = jj ? a01 : a00, v1 = jj ? a11 : a10, v2 = jj ? a21 : a20;
      // ring-full guard vs consumer C (rare)
      if (t >= 29) {
        u32 tgt = 8u*(u32)(t - 28);
        if (shadowC < tgt) shadowC = spin_ge(cntC, tgt, shadowC);
      }
      u16* xb_ = slots_xp + (size_t)(t & (RING-1))*8*NG
               + (size_t)(c & 7)*NG + 32*w + jj*16 + q*4;
      st_agent((u64*)(xb_),        pack4(v0));
      st_agent((u64*)(xb_ + NH),   pack4(v1));
      st_agent((u64*)(xb_ + 2*NH), pack4(v2));
      if (l == 0)
        __hip_atomic_fetch_add(cntB, 1u, __ATOMIC_RELEASE, __HIP_MEMORY_SCOPE_AGENT);
      wc0 = pf0; wc1 = pf1;
      if (t + 2 < NT) {
        u32 tgt = 8u*(u32)(t + 3);
        if (shadowA < tgt) shadowA = spin_ge(cntA, tgt, shadowA);
        const u16* sn = slots_h0 + (size_t)((t+2) & (RING-1))*4096 + tid*8;
        pf0 = ld_agent((const u64*)sn); pf1 = ld_agent((const u64*)(sn + 4));
      }
    }

  } else {
    // ================= C: layer-1 recurrence ==============================
    short8 wf[3][2][8];
    load_frags(Whh1, w, c, q, wf);
    float4 bt0 = *(const float4*)&bhh1[2*NH + 32*w + q*4];
    float4 bt1 = *(const float4*)&bhh1[2*NH + 32*w + q*4 + 16];
    f32x4 bhn0; bhn0[0]=bt0.x; bhn0[1]=bt0.y; bhn0[2]=bt0.z; bhn0[3]=bt0.w;
    f32x4 bhn1; bhn1[0]=bt1.x; bhn1[1]=bt1.y; bhn1[2]=bt1.z; bhn1[3]=bt1.w;
    const int jh = c >> 3;
    const bool lo8 = (jh == 0);
    const int bb = b0 + (c & 7);
    const int jb = 32*w + jh*16 + q*4;
    const int lp = (c&7) + 16*(2*jh + (q>>1));
    const size_t xoff = (size_t)(c & 7)*NG + jb;
    u32 shadowB = 0;
    // ---- startup LAG: let B get LAG steps ahead before we consume ----
    shadowB = spin_ge(cntB, 8u*LAG, shadowB);
    u64 vr = ld_agent((const u64*)(slots_xp + xoff));
    u64 vz = ld_agent((const u64*)(slots_xp + xoff + NH));
    u64 vn = ld_agent((const u64*)(slots_xp + xoff + 2*NH));
    uint2 xpr, xpz, xpn;
    xpr.x=(u32)vr; xpr.y=(u32)(vr>>32);
    xpz.x=(u32)vz; xpz.y=(u32)(vz>>32);
    xpn.x=(u32)vn; xpn.y=(u32)(vn>>32);
    u64 pr = ld_agent((const u64*)(slots_xp + 1*8*NG + xoff));
    u64 pz = ld_agent((const u64*)(slots_xp + 1*8*NG + xoff + NH));
    u64 pn = ld_agent((const u64*)(slots_xp + 1*8*NG + xoff + 2*NH));
    uint2 hpk; hpk.x = 0u; hpk.y = 0u;

    #pragma unroll 1
    for (int t = 0; t < NT; ++t) {
      const int cur = t & 1, nxt = cur ^ 1;
      short8 bfr[8];
      #pragma unroll
      for (int kb = 0; kb < 8; ++kb) bfr[kb] = *(const short8*)&hfrag[cur][kb][l*8];
      f32x4 z4 = {0.f,0.f,0.f,0.f};
      f32x4 ar0 = z4, az0 = z4, ar1 = z4, az1 = z4;
      f32x4 an0 = bhn0, an1 = bhn1;
      #pragma unroll
      for (int kb = 0; kb < 8; ++kb) {
        short8 bv = bfr[kb];
        ar0 = __builtin_amdgcn_mfma_f32_16x16x32_bf16(wf[0][0][kb], bv, ar0, 0,0,0);
        az0 = __builtin_amdgcn_mfma_f32_16x16x32_bf16(wf[1][0][kb], bv, az0, 0,0,0);
        an0 = __builtin_amdgcn_mfma_f32_16x16x32_bf16(wf[2][0][kb], bv, an0, 0,0,0);
        ar1 = __builtin_amdgcn_mfma_f32_16x16x32_bf16(wf[0][1][kb], bv, ar1, 0,0,0);
        az1 = __builtin_amdgcn_mfma_f32_16x16x32_bf16(wf[1][1][kb], bv, az1, 0,0,0);
        an1 = __builtin_amdgcn_mfma_f32_16x16x32_bf16(wf[2][1][kb], bv, an1, 0,0,0);
      }
      float hv[4];
      #pragma unroll
      for (int r = 0; r < 4; ++r) {
        float arv = lo8 ? ar0[r] : ar1[r];
        float azv = lo8 ? az0[r] : az1[r];
        float anv = lo8 ? an0[r] : an1[r];
        u32 xrw = (r < 2) ? xpr.x : xpr.y;
        u32 xzw = (r < 2) ? xpz.x : xpz.y;
        u32 xnw = (r < 2) ? xpn.x : xpn.y;
        u32 hpw = (r < 2) ? hpk.x : hpk.y;
        float xr = (r & 1) ? hi_bf(xrw) : lo_bf(xrw);
        float xz = (r & 1) ? hi_bf(xzw) : lo_bf(xzw);
        float xn = (r & 1) ? hi_bf(xnw) : lo_bf(xnw);
        float hp = (r & 1) ? hi_bf(hpw) : lo_bf(hpw);
        float rr = sigf(xr + arv);
        float zz = sigf(xz + azv);
        float nn = tanhf_(__builtin_fmaf(rr, anv, xn));
        hv[r] = __builtin_fmaf(zz, hp - nn, nn);
      }
      hpk.x = pack_rne(hv[0], hv[1]);
      hpk.y = pack_rne(hv[2], hv[3]);

      u16* hdst = &hfrag[nxt][w][lp*8 + (q&1)*4];
      *(uint2*)hdst        = hpk;
      *(uint2*)(hdst + 64) = hpk;
      if (t == NT-1)
        *(uint2*)&hT[(size_t)bb*NH + jb] = hpk;
      if (l == 0)
        __hip_atomic_fetch_add(cntC, 1u, __ATOMIC_RELEASE, __HIP_MEMORY_SCOPE_AGENT);

      // rotate + depth-2 guarded prefetch
      xpr.x=(u32)pr; xpr.y=(u32)(pr>>32);
      xpz.x=(u32)pz; xpz.y=(u32)(pz>>32);
      xpn.x=(u32)pn; xpn.y=(u32)(pn>>32);
      if (t + 2 < NT) {
        u32 tgt = 8u*(u32)(t + 3);
        if (shadowB < tgt) shadowB = spin_ge(cntB, tgt, shadowB);
        const u16* sn = slots_xp + (size_t)((t+2) & (RING-1))*8*NG + xoff;
        pr = ld_agent((const u64*)(sn));
        pz = ld_agent((const u64*)(sn + NH));
        pn = ld_agent((const u64*)(sn + 2*NH));
      }
      asm volatile("s_waitcnt lgkmcnt(0)" ::: "memory");
      __builtin_amdgcn_s_barrier();
      __builtin_amdgcn_sched_barrier(0);
    }
  }
}

// ---------------------------------------------------------------------------
__global__ __launch_bounds__(256) void fc_kernel(const u16* __restrict__ hT,
    const float* __restrict__ Wfc, const float* __restrict__ bfc, float* __restrict__ out)
{
  __shared__ float wv[NH];
  int tid = threadIdx.x;
  if (tid < NH) wv[tid] = Wfc[tid];
  __syncthreads();
  if (tid < NB) {
    float acc = bfc[0];
    for (int j = 0; j < NH; ++j) acc += lo_bf((u32)hT[tid*NH + j]) * wv[j];
    out[tid] = sigf(acc);
  }
}

// ---------------------------------------------------------------------------
extern "C" void kernel_launch(void* const* d_in, const int* in_sizes, int n_in,
                              void* d_out, int out_size, void* d_ws, size_t ws_size,
                              hipStream_t stream) {
  const float* x    = (const float*)d_in[0];
  const float* Wih0 = (const float*)d_in[1];
  const float* Whh0 = (const float*)d_in[2];
  const float* bih0 = (const float*)d_in[3];
  const float* bhh0 = (const float*)d_in[4];
  const float* Wih1 = (const float*)d_in[5];
  const float* Whh1 = (const float*)d_in[6];
  const float* bih1 = (const float*)d_in[7];
  const float* bhh1 = (const float*)d_in[8];
  const float* Wfc  = (const float*)d_in[9];
  const float* bfc  = (const float*)d_in[10];

  char* ws = (char*)d_ws;
  u16*   xproj   = (u16*)ws;                                 // 100,663,296 B
  u16*   xbf     = (u16*)(ws + 100663296);                   // 33.5 MB (dead after GEMM0)
  u16*   fifo_h0 = (u16*)(ws + 100663296);                   // 4 MB   (overlays xbf)
  u16*   fifo_xp = (u16*)(ws + 100663296 + 4194304);         // 6 MB   (overlays xbf)
  u32*   cnts    = (u32*)(ws + 100663296 + 4194304 + 6291456); // 6 KB (overlays xbf)
  u16*   w0bf    = (u16*)(ws + 134217728);                   // 384 KB
  float* bias0   = (float*)(ws + 135004160);                 // 3 KB
  u16*   hT      = (u16*)(ws + 135010304);                   // 64 KB

  convert_kernel<<<dim3(2048), dim3(256), 0, stream>>>(
      x, Wih0, bih0, bhh0, xbf, w0bf, bias0);
  gemm_proj<<<dim3(1024*24), dim3(256), 0, stream>>>(xbf, w0bf, bias0, xproj);
  hipMemsetAsync(cnts, 0, 3*NGRP*32*sizeof(u32), stream);
  pipeline_kernel<<<dim3(48), dim3(512), 0, stream>>>(
      xproj, Whh0, bhh0, Wih1, bih1, bhh1, Whh1, hT, fifo_h0, fifo_xp, cnts);
  fc_kernel<<<dim3(1), dim3(256), 0, stream>>>(hT, Wfc, bfc, (float*)d_out);
}

// Round 7
// 1443.258 us; speedup vs baseline: 2.3954x; 2.3954x over previous
//
#include <hip/hip_runtime.h>
#include <hip/hip_bf16.h>
#include <stdint.h>

#define NB 128
#define NT 512
#define NI 256
#define NH 256
#define NG 768          // 3*NH
#define NGRP 16         // batch groups (8 batches each)
#define RING 32         // FIFO ring slots
#define LAGB 2          // startup lag in 8-step blocks (16 steps)

typedef unsigned int u32;
typedef unsigned long long u64;
typedef unsigned short u16;
typedef __attribute__((ext_vector_type(8))) short short8;
typedef __attribute__((ext_vector_type(4))) float f32x4;

__device__ __forceinline__ float lo_bf(u32 u){ return __uint_as_float(u << 16); }
__device__ __forceinline__ float hi_bf(u32 u){ return __uint_as_float(u & 0xffff0000u); }
__device__ __forceinline__ u16 f2bf(float f){
  u32 u = __float_as_uint(f);
  u += 0x7fffu + ((u >> 16) & 1u);   // RNE
  return (u16)(u >> 16);
}
__device__ __forceinline__ u32 pack2(float a, float b){
  return (u32)f2bf(a) | ((u32)f2bf(b) << 16);
}
__device__ __forceinline__ u32 pack_rne(float a, float b){
  u32 ua = __float_as_uint(a), ub = __float_as_uint(b);
  ua += 0x7fffu + ((ua >> 16) & 1u);
  ub += 0x7fffu + ((ub >> 16) & 1u);
  return (ua >> 16) | (ub & 0xffff0000u);
}
__device__ __forceinline__ u64 pack4(const f32x4& v){
  u32 a = pack_rne(v[0], v[1]), b = pack_rne(v[2], v[3]);
  return (u64)a | ((u64)b << 32);
}
__device__ __forceinline__ float sigf(float v){
  return __builtin_amdgcn_rcpf(1.f + __expf(-v));
}
__device__ __forceinline__ float tanhf_(float u){
  float e = __expf(2.f*u);
  return 1.f - 2.f*__builtin_amdgcn_rcpf(e + 1.f);
}
__device__ __forceinline__ void gload_lds16(const void* g, void* l){
  __builtin_amdgcn_global_load_lds((const __attribute__((address_space(1))) void*)g,
                                   (__attribute__((address_space(3))) void*)l, 16, 0, 0);
}
__device__ __forceinline__ void st_agent(u64* p, u64 v){
  __hip_atomic_store(p, v, __ATOMIC_RELAXED, __HIP_MEMORY_SCOPE_AGENT);
}
__device__ __forceinline__ u64 ld_agent(const u64* p){
  return __hip_atomic_load(p, __ATOMIC_RELAXED, __HIP_MEMORY_SCOPE_AGENT);
}
// relaxed shadowed spin (data travels via agent-scope ops -> no acquire needed)
__device__ __forceinline__ u32 spin_rel(u32* p, u32 target, u32 shadow){
  while (shadow < target) {
    shadow = __hip_atomic_load(p, __ATOMIC_RELAXED, __HIP_MEMORY_SCOPE_AGENT);
    if (shadow >= target) break;
    __builtin_amdgcn_s_sleep(2);
  }
  return shadow;
}
// resident 768x256 weight slice -> 48 A-frags per wave (rows g*NH+32w+jj*16+c)
__device__ __forceinline__ void load_frags(const float* W, int w, int c, int q,
                                           short8 wf[3][2][8]){
  #pragma unroll
  for (int g = 0; g < 3; ++g)
    #pragma unroll
    for (int jj = 0; jj < 2; ++jj) {
      const float* src = W + ((size_t)(g*NH + 32*w + jj*16 + c))*NI + q*8;
      #pragma unroll
      for (int kb = 0; kb < 8; ++kb) {
        float4 f0 = *(const float4*)(src + kb*32);
        float4 f1 = *(const float4*)(src + kb*32 + 4);
        short8 s;
        s[0]=(short)f2bf(f0.x); s[1]=(short)f2bf(f0.y);
        s[2]=(short)f2bf(f0.z); s[3]=(short)f2bf(f0.w);
        s[4]=(short)f2bf(f1.x); s[5]=(short)f2bf(f1.y);
        s[6]=(short)f2bf(f1.z); s[7]=(short)f2bf(f1.w);
        wf[g][jj][kb] = s;
      }
    }
}

// ---------------------------------------------------------------------------
__global__ void convert_kernel(const float* __restrict__ x,
    const float* __restrict__ Wih0,
    const float* __restrict__ bih0, const float* __restrict__ bhh0,
    u16* __restrict__ xbf, u16* __restrict__ w0bf, float* __restrict__ bias0)
{
  const int NX4 = NB*NT*NI/4, NW4 = NG*NH/4;
  int gid = blockIdx.x*blockDim.x + threadIdx.x;
  for (int i = gid; i < NX4 + NW4; i += gridDim.x*blockDim.x) {
    const float* s; u16* d; int o;
    if (i < NX4) { s = x;    d = xbf;  o = i; }
    else         { s = Wih0; d = w0bf; o = i - NX4; }
    float4 v = *(const float4*)(s + (size_t)o*4);
    uint2 pk; pk.x = pack2(v.x, v.y); pk.y = pack2(v.z, v.w);
    *(uint2*)&d[(size_t)o*4] = pk;
  }
  if (gid < NG) bias0[gid] = bih0[gid] + (gid < 2*NH ? bhh0[gid] : 0.f);
}

// ---------------------------------------------------------------------------
// xproj0[m][g] = sum_k xbf[m][k] * w0bf[g][k] + bias0[g]
// ---------------------------------------------------------------------------
__global__ __launch_bounds__(256, 2) void gemm_proj(const u16* __restrict__ A,
    const u16* __restrict__ W, const float* __restrict__ bias, u16* __restrict__ out)
{
  const int mt = blockIdx.x / 24, nt = blockIdx.x % 24;
  __shared__ __align__(16) u16 As[64*256];
  __shared__ __align__(16) u16 Bs[32*256];
  const int tid = threadIdx.x;
  const u16* Ag = A + (size_t)mt*64*256;
  const u16* Wg = W + (size_t)nt*32*256;
  #pragma unroll
  for (int i = 0; i < 8; ++i) {
    int ca = tid + 256*i, row = ca >> 5, sl = ca & 31;
    gload_lds16(Ag + row*256 + ((sl ^ (row&7))<<3), &As[ca<<3]);
  }
  #pragma unroll
  for (int i = 0; i < 4; ++i) {
    int cb = tid + 256*i, row = cb >> 5, sl = cb & 31;
    gload_lds16(Wg + row*256 + ((sl ^ (row&7))<<3), &Bs[cb<<3]);
  }
  __syncthreads();
  const int w = tid >> 6, l = tid & 63, c = l & 15, q = l >> 4;
  f32x4 acc0 = {0.f,0.f,0.f,0.f}, acc1 = acc0;
  const int arow = w*16 + c;
  #pragma unroll
  for (int kb = 0; kb < 8; ++kb) {
    int ks = kb*4 + q;
    short8 af  = *(const short8*)&As[arow*256 + ((ks ^ (arow&7))<<3)];
    short8 bf0 = *(const short8*)&Bs[c*256        + ((ks ^ (c&7))<<3)];
    short8 bf1 = *(const short8*)&Bs[(16+c)*256   + ((ks ^ ((16+c)&7))<<3)];
    acc0 = __builtin_amdgcn_mfma_f32_16x16x32_bf16(af, bf0, acc0, 0,0,0);
    acc1 = __builtin_amdgcn_mfma_f32_16x16x32_bf16(af, bf1, acc1, 0,0,0);
  }
  #pragma unroll
  for (int nf = 0; nf < 2; ++nf) {
    int g = nt*32 + nf*16 + c;
    float bs = bias[g];
    f32x4 av = nf ? acc1 : acc0;
    #pragma unroll
    for (int r = 0; r < 4; ++r) {
      int m = mt*64 + w*16 + q*4 + r;
      out[(size_t)m*NG + g] = f2bf(av[r] + bs);
    }
  }
}

// ---------------------------------------------------------------------------
// 3-stage layer pipeline, BATCHED sync (counters published once per 8 steps,
// relaxed; data via per-step relaxed agent-scope stores/loads -> no per-step
// fences). 48 wgs x 512 thr. role = blockIdx>>4, g_ = blockIdx&15.
// ---------------------------------------------------------------------------
__global__ __launch_bounds__(512, 1) void pipeline_kernel(
    const u16*  __restrict__ xproj,   // [NB*NT][768] bf16 (bias0 folded)
    const float* __restrict__ Whh0, const float* __restrict__ bhh0,
    const float* __restrict__ Wih1, const float* __restrict__ bih1,
    const float* __restrict__ bhh1, const float* __restrict__ Whh1,
    u16* __restrict__ hT,             // [NB][NH] bf16
    u16* __restrict__ fifo_h0,        // [NGRP][RING][4096] u16 (8KB frag images)
    u16* __restrict__ fifo_xp,        // [NGRP][RING][8*NG] bf16 (12KB slots)
    u32* __restrict__ cnts)           // [3][NGRP][32]
{
  const int role = blockIdx.x >> 4;
  const int g_   = blockIdx.x & 15;
  const int b0   = g_*8;
  const int tid = threadIdx.x;
  const int w = tid >> 6, l = tid & 63, c = l & 15, q = l >> 4;

  u32* cntA = cnts + (0*NGRP + g_)*32;
  u32* cntB = cnts + (1*NGRP + g_)*32;
  u32* cntC = cnts + (2*NGRP + g_)*32;
  u16* slots_h0 = fifo_h0 + (size_t)g_*RING*4096;
  u16* slots_xp = fifo_xp + (size_t)g_*RING*8*NG;

  __shared__ __align__(16) u16 hfrag[2][8][512];   // 16 KB
  for (int i = tid; i < 4096; i += 512) ((u32*)hfrag)[i] = 0u;
  __syncthreads();

  if (role == 0) {
    // ================= A: layer-0 recurrence (R3 engine) ==================
    short8 wf[3][2][8];
    load_frags(Whh0, w, c, q, wf);
    float4 bt0 = *(const float4*)&bhh0[2*NH + 32*w + q*4];
    float4 bt1 = *(const float4*)&bhh0[2*NH + 32*w + q*4 + 16];
    f32x4 bhn0; bhn0[0]=bt0.x; bhn0[1]=bt0.y; bhn0[2]=bt0.z; bhn0[3]=bt0.w;
    f32x4 bhn1; bhn1[0]=bt1.x; bhn1[1]=bt1.y; bhn1[2]=bt1.z; bhn1[3]=bt1.w;
    const int jh = c >> 3;
    const bool lo8 = (jh == 0);
    const int bb = b0 + (c & 7);
    const int jb = 32*w + jh*16 + q*4;
    const u16* xptr = xproj + (size_t)bb*NT*NG + jb;
    uint2 xpr = *(const uint2*)(xptr);
    uint2 xpz = *(const uint2*)(xptr + NH);
    uint2 xpn = *(const uint2*)(xptr + 2*NH);
    const u16* x1 = xptr + NG;
    uint2 pfr = *(const uint2*)(x1);
    uint2 pfz = *(const uint2*)(x1 + NH);
    uint2 pfn = *(const uint2*)(x1 + 2*NH);
    uint2 hpk; hpk.x = 0u; hpk.y = 0u;
    const int lp = (c&7) + 16*(2*jh + (q>>1));
    const int foff = w*512 + lp*8 + (q&1)*4;     // u16 units in 8KB slot
    u32 shadowB = 0;

    #pragma unroll 1
    for (int t = 0; t < NT; ++t) {
      const int cur = t & 1, nxt = cur ^ 1;
      short8 bfr[8];
      #pragma unroll
      for (int kb = 0; kb < 8; ++kb) bfr[kb] = *(const short8*)&hfrag[cur][kb][l*8];
      f32x4 z4 = {0.f,0.f,0.f,0.f};
      f32x4 ar0 = z4, az0 = z4, ar1 = z4, az1 = z4;
      f32x4 an0 = bhn0, an1 = bhn1;
      #pragma unroll
      for (int kb = 0; kb < 8; ++kb) {
        short8 bv = bfr[kb];
        ar0 = __builtin_amdgcn_mfma_f32_16x16x32_bf16(wf[0][0][kb], bv, ar0, 0,0,0);
        az0 = __builtin_amdgcn_mfma_f32_16x16x32_bf16(wf[1][0][kb], bv, az0, 0,0,0);
        an0 = __builtin_amdgcn_mfma_f32_16x16x32_bf16(wf[2][0][kb], bv, an0, 0,0,0);
        ar1 = __builtin_amdgcn_mfma_f32_16x16x32_bf16(wf[0][1][kb], bv, ar1, 0,0,0);
        az1 = __builtin_amdgcn_mfma_f32_16x16x32_bf16(wf[1][1][kb], bv, az1, 0,0,0);
        an1 = __builtin_amdgcn_mfma_f32_16x16x32_bf16(wf[2][1][kb], bv, an1, 0,0,0);
      }
      float hv[4];
      #pragma unroll
      for (int r = 0; r < 4; ++r) {
        float arv = lo8 ? ar0[r] : ar1[r];
        float azv = lo8 ? az0[r] : az1[r];
        float anv = lo8 ? an0[r] : an1[r];
        u32 xrw = (r < 2) ? xpr.x : xpr.y;
        u32 xzw = (r < 2) ? xpz.x : xpz.y;
        u32 xnw = (r < 2) ? xpn.x : xpn.y;
        u32 hpw = (r < 2) ? hpk.x : hpk.y;
        float xr = (r & 1) ? hi_bf(xrw) : lo_bf(xrw);
        float xz = (r & 1) ? hi_bf(xzw) : lo_bf(xzw);
        float xn = (r & 1) ? hi_bf(xnw) : lo_bf(xnw);
        float hp = (r & 1) ? hi_bf(hpw) : lo_bf(hpw);
        float rr = sigf(xr + arv);
        float zz = sigf(xz + azv);
        float nn = tanhf_(__builtin_fmaf(rr, anv, xn));
        hv[r] = __builtin_fmaf(zz, hp - nn, nn);
      }
      hpk.x = pack_rne(hv[0], hv[1]);
      hpk.y = pack_rne(hv[2], hv[3]);

      u16* hdst = &hfrag[nxt][w][lp*8 + (q&1)*4];
      *(uint2*)hdst        = hpk;
      *(uint2*)(hdst + 64) = hpk;

      // ring-full guard (batched targets, shadowed -> rare polls)
      if (t >= 32) {
        u32 tgt = (u32)(t - 24) >> 3;
        if (shadowB < tgt) shadowB = spin_rel(cntB, tgt, shadowB);
      }
      // publish h0 frag image (relaxed agent stores, fire-and-forget)
      u64 hv64 = (u64)hpk.x | ((u64)hpk.y << 32);
      u16* sb = slots_h0 + (size_t)(t & (RING-1))*4096 + foff;
      st_agent((u64*)sb, hv64);
      st_agent((u64*)(sb + 64), hv64);
      // batched counter publish: once per 8 steps, relaxed add after vmcnt drain
      if ((t & 7) == 7) {
        asm volatile("s_waitcnt vmcnt(0)" ::: "memory");
        if (l == 0)
          __hip_atomic_fetch_add(cntA, 1u, __ATOMIC_RELAXED, __HIP_MEMORY_SCOPE_AGENT);
      }

      // depth-2 xproj prefetch
      xpr = pfr; xpz = pfz; xpn = pfn;
      if (t + 2 < NT) {
        const u16* xn_ = xptr + (size_t)(t+2)*NG;
        pfr = *(const uint2*)(xn_);
        pfz = *(const uint2*)(xn_ + NH);
        pfn = *(const uint2*)(xn_ + 2*NH);
      }
      asm volatile("s_waitcnt lgkmcnt(0)" ::: "memory");
      __builtin_amdgcn_s_barrier();
      __builtin_amdgcn_sched_barrier(0);
    }

  } else if (role == 1) {
    // ================= B: xp1[t] = Wih1 * h0[t] + bias1 ===================
    short8 wf[3][2][8];
    load_frags(Wih1, w, c, q, wf);
    f32x4 bias[3][2];
    #pragma unroll
    for (int g = 0; g < 3; ++g)
      #pragma unroll
      for (int jj = 0; jj < 2; ++jj) {
        int grow = g*NH + 32*w + jj*16 + q*4;
        float4 bi = *(const float4*)&bih1[grow];
        f32x4 bv; bv[0]=bi.x; bv[1]=bi.y; bv[2]=bi.z; bv[3]=bi.w;
        if (g < 2) {
          float4 bh = *(const float4*)&bhh1[grow];
          bv[0]+=bh.x; bv[1]+=bh.y; bv[2]+=bh.z; bv[3]+=bh.w;
        }
        bias[g][jj] = bv;
      }
    const int jj = c >> 3;
    u32 shadowA = 0, shadowC = 0;
    // ---- startup lag: A must be LAGB blocks (16 steps) ahead ----
    shadowA = spin_rel(cntA, LAGB, shadowA);
    const u16* s0 = slots_h0 + 0*4096 + tid*8;
    u64 wc0 = ld_agent((const u64*)s0), wc1 = ld_agent((const u64*)(s0 + 4));
    const u16* s1 = slots_h0 + 1*4096 + tid*8;
    u64 pf0 = ld_agent((const u64*)s1), pf1 = ld_agent((const u64*)(s1 + 4));

    #pragma unroll 1
    for (int t = 0; t < NT; ++t) {
      const int buf = t & 1;
      uint4 wv; wv.x=(u32)wc0; wv.y=(u32)(wc0>>32); wv.z=(u32)wc1; wv.w=(u32)(wc1>>32);
      *(uint4*)&((u16*)hfrag)[buf*4096 + tid*8] = wv;
      asm volatile("s_waitcnt lgkmcnt(0)" ::: "memory");
      __builtin_amdgcn_s_barrier();
      __builtin_amdgcn_sched_barrier(0);

      f32x4 a00 = bias[0][0], a10 = bias[1][0], a20 = bias[2][0];
      f32x4 a01 = bias[0][1], a11 = bias[1][1], a21 = bias[2][1];
      #pragma unroll
      for (int kb = 0; kb < 8; ++kb) {
        short8 bv = *(const short8*)&hfrag[buf][kb][l*8];
        a00 = __builtin_amdgcn_mfma_f32_16x16x32_bf16(wf[0][0][kb], bv, a00, 0,0,0);
        a10 = __builtin_amdgcn_mfma_f32_16x16x32_bf16(wf[1][0][kb], bv, a10, 0,0,0);
        a20 = __builtin_amdgcn_mfma_f32_16x16x32_bf16(wf[2][0][kb], bv, a20, 0,0,0);
        a01 = __builtin_amdgcn_mfma_f32_16x16x32_bf16(wf[0][1][kb], bv, a01, 0,0,0);
        a11 = __builtin_amdgcn_mfma_f32_16x16x32_bf16(wf[1][1][kb], bv, a11, 0,0,0);
        a21 = __builtin_amdgcn_mfma_f32_16x16x32_bf16(wf[2][1][kb], bv, a21, 0,0,0);
      }
      f32x4 v0 = jj ? a01 : a00, v1 = jj ? a11 : a10, v2 = jj ? a21 : a20;
      // ring-full guard vs consumer C (batched, shadowed)
      if (t >= 32) {
        u32 tgt = (u32)(t - 24) >> 3;
        if (shadowC < tgt) shadowC = spin_rel(cntC, tgt, shadowC);
      }
      u16* xb_ = slots_xp + (size_t)(t & (RING-1))*8*NG
               + (size_t)(c & 7)*NG + 32*w + jj*16 + q*4;
      st_agent((u64*)(xb_),        pack4(v0));
      st_agent((u64*)(xb_ + NH),   pack4(v1));
      st_agent((u64*)(xb_ + 2*NH), pack4(v2));
      if ((t & 7) == 7) {
        asm volatile("s_waitcnt vmcnt(0)" ::: "memory");
        if (l == 0)
          __hip_atomic_fetch_add(cntB, 1u, __ATOMIC_RELAXED, __HIP_MEMORY_SCOPE_AGENT);
      }
      wc0 = pf0; wc1 = pf1;
      if (t + 2 < NT) {
        u32 tgt = ((u32)(t + 2) >> 3) + 1;
        if (shadowA < tgt) shadowA = spin_rel(cntA, tgt, shadowA);
        const u16* sn = slots_h0 + (size_t)((t+2) & (RING-1))*4096 + tid*8;
        pf0 = ld_agent((const u64*)sn); pf1 = ld_agent((const u64*)(sn + 4));
      }
    }

  } else {
    // ================= C: layer-1 recurrence ==============================
    short8 wf[3][2][8];
    load_frags(Whh1, w, c, q, wf);
    float4 bt0 = *(const float4*)&bhh1[2*NH + 32*w + q*4];
    float4 bt1 = *(const float4*)&bhh1[2*NH + 32*w + q*4 + 16];
    f32x4 bhn0; bhn0[0]=bt0.x; bhn0[1]=bt0.y; bhn0[2]=bt0.z; bhn0[3]=bt0.w;
    f32x4 bhn1; bhn1[0]=bt1.x; bhn1[1]=bt1.y; bhn1[2]=bt1.z; bhn1[3]=bt1.w;
    const int jh = c >> 3;
    const bool lo8 = (jh == 0);
    const int bb = b0 + (c & 7);
    const int jb = 32*w + jh*16 + q*4;
    const int lp = (c&7) + 16*(2*jh + (q>>1));
    const size_t xoff = (size_t)(c & 7)*NG + jb;
    u32 shadowB = 0;
    // ---- startup lag: B must be LAGB blocks (16 steps) ahead ----
    shadowB = spin_rel(cntB, LAGB, shadowB);
    u64 vr = ld_agent((const u64*)(slots_xp + xoff));
    u64 vz = ld_agent((const u64*)(slots_xp + xoff + NH));
    u64 vn = ld_agent((const u64*)(slots_xp + xoff + 2*NH));
    uint2 xpr, xpz, xpn;
    xpr.x=(u32)vr; xpr.y=(u32)(vr>>32);
    xpz.x=(u32)vz; xpz.y=(u32)(vz>>32);
    xpn.x=(u32)vn; xpn.y=(u32)(vn>>32);
    u64 pr = ld_agent((const u64*)(slots_xp + 1*8*NG + xoff));
    u64 pz = ld_agent((const u64*)(slots_xp + 1*8*NG + xoff + NH));
    u64 pn = ld_agent((const u64*)(slots_xp + 1*8*NG + xoff + 2*NH));
    uint2 hpk; hpk.x = 0u; hpk.y = 0u;

    #pragma unroll 1
    for (int t = 0; t < NT; ++t) {
      const int cur = t & 1, nxt = cur ^ 1;
      short8 bfr[8];
      #pragma unroll
      for (int kb = 0; kb < 8; ++kb) bfr[kb] = *(const short8*)&hfrag[cur][kb][l*8];
      f32x4 z4 = {0.f,0.f,0.f,0.f};
      f32x4 ar0 = z4, az0 = z4, ar1 = z4, az1 = z4;
      f32x4 an0 = bhn0, an1 = bhn1;
      #pragma unroll
      for (int kb = 0; kb < 8; ++kb) {
        short8 bv = bfr[kb];
        ar0 = __builtin_amdgcn_mfma_f32_16x16x32_bf16(wf[0][0][kb], bv, ar0, 0,0,0);
        az0 = __builtin_amdgcn_mfma_f32_16x16x32_bf16(wf[1][0][kb], bv, az0, 0,0,0);
        an0 = __builtin_amdgcn_mfma_f32_16x16x32_bf16(wf[2][0][kb], bv, an0, 0,0,0);
        ar1 = __builtin_amdgcn_mfma_f32_16x16x32_bf16(wf[0][1][kb], bv, ar1, 0,0,0);
        az1 = __builtin_amdgcn_mfma_f32_16x16x32_bf16(wf[1][1][kb], bv, az1, 0,0,0);
        an1 = __builtin_amdgcn_mfma_f32_16x16x32_bf16(wf[2][1][kb], bv, an1, 0,0,0);
      }
      float hv[4];
      #pragma unroll
      for (int r = 0; r < 4; ++r) {
        float arv = lo8 ? ar0[r] : ar1[r];
        float azv = lo8 ? az0[r] : az1[r];
        float anv = lo8 ? an0[r] : an1[r];
        u32 xrw = (r < 2) ? xpr.x : xpr.y;
        u32 xzw = (r < 2) ? xpz.x : xpz.y;
        u32 xnw = (r < 2) ? xpn.x : xpn.y;
        u32 hpw = (r < 2) ? hpk.x : hpk.y;
        float xr = (r & 1) ? hi_bf(xrw) : lo_bf(xrw);
        float xz = (r & 1) ? hi_bf(xzw) : lo_bf(xzw);
        float xn = (r & 1) ? hi_bf(xnw) : lo_bf(xnw);
        float hp = (r & 1) ? hi_bf(hpw) : lo_bf(hpw);
        float rr = sigf(xr + arv);
        float zz = sigf(xz + azv);
        float nn = tanhf_(__builtin_fmaf(rr, anv, xn));
        hv[r] = __builtin_fmaf(zz, hp - nn, nn);
      }
      hpk.x = pack_rne(hv[0], hv[1]);
      hpk.y = pack_rne(hv[2], hv[3]);

      u16* hdst = &hfrag[nxt][w][lp*8 + (q&1)*4];
      *(uint2*)hdst        = hpk;
      *(uint2*)(hdst + 64) = hpk;
      if (t == NT-1)
        *(uint2*)&hT[(size_t)bb*NH + jb] = hpk;
      // batched completion publish (C's loads were register-consumed already)
      if ((t & 7) == 7 && l == 0)
        __hip_atomic_fetch_add(cntC, 1u, __ATOMIC_RELAXED, __HIP_MEMORY_SCOPE_AGENT);

      // rotate + depth-2 guarded prefetch (batched target, shadowed)
      xpr.x=(u32)pr; xpr.y=(u32)(pr>>32);
      xpz.x=(u32)pz; xpz.y=(u32)(pz>>32);
      xpn.x=(u32)pn; xpn.y=(u32)(pn>>32);
      if (t + 2 < NT) {
        u32 tgt = ((u32)(t + 2) >> 3) + 1;
        if (shadowB < tgt) shadowB = spin_rel(cntB, tgt, shadowB);
        const u16* sn = slots_xp + (size_t)((t+2) & (RING-1))*8*NG + xoff;
        pr = ld_agent((const u64*)(sn));
        pz = ld_agent((const u64*)(sn + NH));
        pn = ld_agent((const u64*)(sn + 2*NH));
      }
      asm volatile("s_waitcnt lgkmcnt(0)" ::: "memory");
      __builtin_amdgcn_s_barrier();
      __builtin_amdgcn_sched_barrier(0);
    }
  }
}

// ---------------------------------------------------------------------------
__global__ __launch_bounds__(256) void fc_kernel(const u16* __restrict__ hT,
    const float* __restrict__ Wfc, const float* __restrict__ bfc, float* __restrict__ out)
{
  __shared__ float wv[NH];
  int tid = threadIdx.x;
  if (tid < NH) wv[tid] = Wfc[tid];
  __syncthreads();
  if (tid < NB) {
    float acc = bfc[0];
    for (int j = 0; j < NH; ++j) acc += lo_bf((u32)hT[tid*NH + j]) * wv[j];
    out[tid] = sigf(acc);
  }
}

// ---------------------------------------------------------------------------
extern "C" void kernel_launch(void* const* d_in, const int* in_sizes, int n_in,
                              void* d_out, int out_size, void* d_ws, size_t ws_size,
                              hipStream_t stream) {
  const float* x    = (const float*)d_in[0];
  const float* Wih0 = (const float*)d_in[1];
  const float* Whh0 = (const float*)d_in[2];
  const float* bih0 = (const float*)d_in[3];
  const float* bhh0 = (const float*)d_in[4];
  const float* Wih1 = (const float*)d_in[5];
  const float* Whh1 = (const float*)d_in[6];
  const float* bih1 = (const float*)d_in[7];
  const float* bhh1 = (const float*)d_in[8];
  const float* Wfc  = (const float*)d_in[9];
  const float* bfc  = (const float*)d_in[10];

  char* ws = (char*)d_ws;
  u16*   xproj   = (u16*)ws;                                 // 100,663,296 B
  u16*   xbf     = (u16*)(ws + 100663296);                   // 33.5 MB (dead after GEMM0)
  u16*   fifo_h0 = (u16*)(ws + 100663296);                   // 4 MB   (overlays xbf)
  u16*   fifo_xp = (u16*)(ws + 100663296 + 4194304);         // 6 MB   (overlays xbf)
  u32*   cnts    = (u32*)(ws + 100663296 + 4194304 + 6291456); // 6 KB (overlays xbf)
  u16*   w0bf    = (u16*)(ws + 134217728);                   // 384 KB
  float* bias0   = (float*)(ws + 135004160);                 // 3 KB
  u16*   hT      = (u16*)(ws + 135010304);                   // 64 KB

  convert_kernel<<<dim3(2048), dim3(256), 0, stream>>>(
      x, Wih0, bih0, bhh0, xbf, w0bf, bias0);
  gemm_proj<<<dim3(1024*24), dim3(256), 0, stream>>>(xbf, w0bf, bias0, xproj);
  hipMemsetAsync(cnts, 0, 3*NGRP*32*sizeof(u32), stream);
  pipeline_kernel<<<dim3(48), dim3(512), 0, stream>>>(
      xproj, Whh0, bhh0, Wih1, bih1, bhh1, Whh1, hT, fifo_h0, fifo_xp, cnts);
  fc_kernel<<<dim3(1), dim3(256), 0, stream>>>(hT, Wfc, bfc, (float*)d_out);
}